// Round 1
// baseline (4522.579 us; speedup 1.0000x reference)
//
#include <hip/hip_runtime.h>

#define N_NODES 50000
#define E_EDGES 800000
#define F 64
#define FE 8
#define H 128
#define MSG_IN 136

__device__ __forceinline__ void fma4(float4& a, float x, const float4& w) {
  a.x = fmaf(x, w.x, a.x); a.y = fmaf(x, w.y, a.y);
  a.z = fmaf(x, w.z, a.z); a.w = fmaf(x, w.w, a.w);
}

// ---------------------------------------------------------------------------
// Edge pass: for a tile of 32 edges, stage X=[vs|cs|ef] (136 f32) in LDS,
// compute hidden_v = relu(X@W1+b1) and hidden_c = relu(X@W1perm+b1) where
// W1perm swaps rows [0,64) <-> [64,128)  (equivalent to swapping vs/cs in the
// concat), then m = hidden @ W2 + b2, atomically scatter-added into agg.
// ---------------------------------------------------------------------------
__global__ __launch_bounds__(256, 1)
void edge_pass(const float* __restrict__ vfeat, const float* __restrict__ cfeat,
               const float* __restrict__ efeat,
               const int* __restrict__ ev, const int* __restrict__ ec,
               const float* __restrict__ w1, const float* __restrict__ b1,
               const float* __restrict__ w2, const float* __restrict__ b2,
               float* __restrict__ aggv, float* __restrict__ aggc)
{
  __shared__ float sW1[MSG_IN * H];     // 69632 B
  __shared__ float sB1[H];
  __shared__ float sB2[F];
  __shared__ float sX[32 * MSG_IN];     // 17408 B, row stride 136 (2-way max)
  __shared__ float sHt[64 * 132];       // 33792 B, rows [v:0..31][c:32..63], stride 132
  __shared__ int   sIv[32], sIc[32];
  // total ~121.9 KB -> 1 block/CU

  const int t = threadIdx.x;
  for (int i = t; i < MSG_IN * H; i += 256) sW1[i] = w1[i];
  if (t < H) sB1[t] = b1[t];
  if (t < F) sB2[t] = b2[t];

  const int lane16 = t & 15, grp = t >> 4;
  const int j0 = lane16 * 4;           // hidden/output column block
  const float4* w2v = (const float4*)w2;  // layer-2 weights from global (L1/L2 broadcast)

  const int nTiles = E_EDGES / 32;     // 25000, exact
  for (int tile = blockIdx.x; tile < nTiles; tile += gridDim.x) {
    __syncthreads();
    // ---- stage X tile (32 rows x 136) ----
    {
      const int tpr = t & 7, r = t >> 3;
      const int e = tile * 32 + r;
      const int iv = ev[e], ic = ec[e];
      if (tpr == 0) { sIv[r] = iv; sIc[r] = ic; }
      const float4* vp = (const float4*)(vfeat + (size_t)iv * F);
      const float4* cp = (const float4*)(cfeat + (size_t)ic * F);
      float4* xr = (float4*)&sX[r * MSG_IN];
      xr[tpr]      = vp[tpr];
      xr[tpr + 8]  = vp[tpr + 8];
      xr[tpr + 16] = cp[tpr];
      xr[tpr + 24] = cp[tpr + 8];
      if (tpr < 2) xr[32 + tpr] = ((const float4*)(efeat + (size_t)e * FE))[tpr];
    }
    __syncthreads();

    // ---- layer 1: 2 edges x 8 cols x 2 mlps per thread ----
    const int e0 = grp * 2, e1 = e0 + 1;
    float4 aV0L = {0,0,0,0}, aV0H = {0,0,0,0}, aV1L = {0,0,0,0}, aV1H = {0,0,0,0};
    float4 aC0L = {0,0,0,0}, aC0H = {0,0,0,0}, aC1L = {0,0,0,0}, aC1H = {0,0,0,0};
    const float* x0p = &sX[e0 * MSG_IN];
    const float* x1p = &sX[e1 * MSG_IN];
    #pragma unroll 4
    for (int k = 0; k < MSG_IN; ++k) {
      const int kp = (k < 64) ? k + 64 : ((k < 128) ? k - 64 : k);
      const float x0 = x0p[k], x1 = x1p[k];
      const float4 wvL = *(const float4*)&sW1[k * H + j0];
      const float4 wvH = *(const float4*)&sW1[k * H + j0 + 64];
      const float4 wcL = *(const float4*)&sW1[kp * H + j0];
      const float4 wcH = *(const float4*)&sW1[kp * H + j0 + 64];
      fma4(aV0L, x0, wvL); fma4(aV0H, x0, wvH);
      fma4(aV1L, x1, wvL); fma4(aV1H, x1, wvH);
      fma4(aC0L, x0, wcL); fma4(aC0H, x0, wcH);
      fma4(aC1L, x1, wcL); fma4(aC1H, x1, wcH);
    }
    // bias + relu -> sHt
    {
      const float4 bL = *(const float4*)&sB1[j0];
      const float4 bH = *(const float4*)&sB1[j0 + 64];
      #define EMIT(row, joff, a, b) { \
        float4 r_ = a; \
        r_.x = fmaxf(r_.x + (b).x, 0.f); r_.y = fmaxf(r_.y + (b).y, 0.f); \
        r_.z = fmaxf(r_.z + (b).z, 0.f); r_.w = fmaxf(r_.w + (b).w, 0.f); \
        *(float4*)&sHt[(row) * 132 + (joff)] = r_; }
      EMIT(e0,      j0,      aV0L, bL); EMIT(e0,      j0 + 64, aV0H, bH);
      EMIT(e1,      j0,      aV1L, bL); EMIT(e1,      j0 + 64, aV1H, bH);
      EMIT(32 + e0, j0,      aC0L, bL); EMIT(32 + e0, j0 + 64, aC0H, bH);
      EMIT(32 + e1, j0,      aC1L, bL); EMIT(32 + e1, j0 + 64, aC1H, bH);
      #undef EMIT
    }
    __syncthreads();

    // ---- layer 2: rows m = grp*4+0..3 (m<32: v, else c), cols f0 = lane16*4 ----
    const int f0 = j0;
    const int m0 = grp * 4;
    float4 a20 = {0,0,0,0}, a21 = {0,0,0,0}, a22 = {0,0,0,0}, a23 = {0,0,0,0};
    #pragma unroll 8
    for (int j = 0; j < H; ++j) {
      const float4 w = w2v[j * 16 + lane16];
      fma4(a20, sHt[(m0 + 0) * 132 + j], w);
      fma4(a21, sHt[(m0 + 1) * 132 + j], w);
      fma4(a22, sHt[(m0 + 2) * 132 + j], w);
      fma4(a23, sHt[(m0 + 3) * 132 + j], w);
    }
    const float4 b2v = *(const float4*)&sB2[f0];
    float4 outs[4] = {a20, a21, a22, a23};
    #pragma unroll
    for (int u = 0; u < 4; ++u) {
      const int m = m0 + u;
      const int mlp = m >> 5, e = m & 31;
      const int idx = mlp ? sIc[e] : sIv[e];
      float* dst = (mlp ? aggc : aggv) + (size_t)idx * F + f0;
      unsafeAtomicAdd(dst + 0, outs[u].x + b2v.x);
      unsafeAtomicAdd(dst + 1, outs[u].y + b2v.y);
      unsafeAtomicAdd(dst + 2, outs[u].z + b2v.z);
      unsafeAtomicAdd(dst + 3, outs[u].w + b2v.w);
    }
  }
}

// ---------------------------------------------------------------------------
// Node update: new_feat = MLP(concat(feat, agg)) with [128->128 relu ->64]
// ---------------------------------------------------------------------------
__global__ __launch_bounds__(256, 1)
void node_update(const float* __restrict__ feat, const float* __restrict__ agg,
                 const float* __restrict__ w1, const float* __restrict__ b1,
                 const float* __restrict__ w2, const float* __restrict__ b2,
                 float* __restrict__ out)
{
  __shared__ float sW1[H * H];          // 65536 B
  __shared__ float sB1[H];
  __shared__ float sB2[F];
  __shared__ float sX[32 * 132];        // 16896 B, padded stride
  __shared__ float sHt[32 * 132];       // 16896 B
  // total ~100 KB

  const int t = threadIdx.x;
  for (int i = t; i < H * H; i += 256) sW1[i] = w1[i];
  if (t < H) sB1[t] = b1[t];
  if (t < F) sB2[t] = b2[t];

  const int lane16 = t & 15, grp = t >> 4;
  const int j0 = lane16 * 4;
  const float4* w2v = (const float4*)w2;

  const int nTiles = (N_NODES + 31) / 32;   // 1563
  for (int tile = blockIdx.x; tile < nTiles; tile += gridDim.x) {
    __syncthreads();
    {
      const int tpr = t & 7, r = t >> 3;
      const int n = tile * 32 + r;
      const int nc = n < N_NODES ? n : N_NODES - 1;
      const float4* fp = (const float4*)(feat + (size_t)nc * F);
      const float4* ap = (const float4*)(agg + (size_t)nc * F);
      float4* xr = (float4*)&sX[r * 132];
      xr[tpr]      = fp[tpr];
      xr[tpr + 8]  = fp[tpr + 8];
      xr[tpr + 16] = ap[tpr];
      xr[tpr + 24] = ap[tpr + 8];
    }
    __syncthreads();

    const int e0 = grp * 2, e1 = e0 + 1;
    float4 a0L = {0,0,0,0}, a0H = {0,0,0,0}, a1L = {0,0,0,0}, a1H = {0,0,0,0};
    const float* x0p = &sX[e0 * 132];
    const float* x1p = &sX[e1 * 132];
    #pragma unroll 4
    for (int k = 0; k < H; ++k) {
      const float x0 = x0p[k], x1 = x1p[k];
      const float4 wL = *(const float4*)&sW1[k * H + j0];
      const float4 wH = *(const float4*)&sW1[k * H + j0 + 64];
      fma4(a0L, x0, wL); fma4(a0H, x0, wH);
      fma4(a1L, x1, wL); fma4(a1H, x1, wH);
    }
    {
      const float4 bL = *(const float4*)&sB1[j0];
      const float4 bH = *(const float4*)&sB1[j0 + 64];
      #define EMITN(row, joff, a, b) { \
        float4 r_ = a; \
        r_.x = fmaxf(r_.x + (b).x, 0.f); r_.y = fmaxf(r_.y + (b).y, 0.f); \
        r_.z = fmaxf(r_.z + (b).z, 0.f); r_.w = fmaxf(r_.w + (b).w, 0.f); \
        *(float4*)&sHt[(row) * 132 + (joff)] = r_; }
      EMITN(e0, j0, a0L, bL); EMITN(e0, j0 + 64, a0H, bH);
      EMITN(e1, j0, a1L, bL); EMITN(e1, j0 + 64, a1H, bH);
      #undef EMITN
    }
    __syncthreads();

    const int f0 = j0;
    float4 a20 = {0,0,0,0}, a21 = {0,0,0,0};
    #pragma unroll 8
    for (int j = 0; j < H; ++j) {
      const float4 w = w2v[j * 16 + lane16];
      fma4(a20, sHt[e0 * 132 + j], w);
      fma4(a21, sHt[e1 * 132 + j], w);
    }
    const float4 b2v = *(const float4*)&sB2[f0];
    const int n0 = tile * 32 + e0;
    if (n0 < N_NODES) {
      float4 o = {a20.x + b2v.x, a20.y + b2v.y, a20.z + b2v.z, a20.w + b2v.w};
      *(float4*)&out[(size_t)n0 * F + f0] = o;
    }
    if (n0 + 1 < N_NODES) {
      float4 o = {a21.x + b2v.x, a21.y + b2v.y, a21.z + b2v.z, a21.w + b2v.w};
      *(float4*)&out[(size_t)(n0 + 1) * F + f0] = o;
    }
  }
}

extern "C" void kernel_launch(void* const* d_in, const int* in_sizes, int n_in,
                              void* d_out, int out_size, void* d_ws, size_t ws_size,
                              hipStream_t stream) {
  const float* var_feat  = (const float*)d_in[0];
  const float* cons_feat = (const float*)d_in[1];
  const float* edge_feat = (const float*)d_in[2];
  const int*   ev        = (const int*)d_in[3];
  const int*   ec        = (const int*)d_in[4];
  const float* w_msg1  = (const float*)d_in[5];
  const float* b_msg1  = (const float*)d_in[6];
  const float* w_msg2  = (const float*)d_in[7];
  const float* b_msg2  = (const float*)d_in[8];
  const float* w_vupd1 = (const float*)d_in[9];
  const float* b_vupd1 = (const float*)d_in[10];
  const float* w_vupd2 = (const float*)d_in[11];
  const float* b_vupd2 = (const float*)d_in[12];
  const float* w_cupd1 = (const float*)d_in[13];
  const float* b_cupd1 = (const float*)d_in[14];
  const float* w_cupd2 = (const float*)d_in[15];
  const float* b_cupd2 = (const float*)d_in[16];

  const size_t NF = (size_t)N_NODES * F;   // 3.2M floats
  float* aggv = (float*)d_ws;
  float* aggc = aggv + NF;
  float* v1   = aggc + NF;
  float* c1   = v1 + NF;
  float* outv = (float*)d_out;
  float* outc = outv + NF;

  for (int it = 0; it < 2; ++it) {
    const float* vf = (it == 0) ? var_feat : v1;
    const float* cf = (it == 0) ? cons_feat : c1;
    float* nv  = (it == 0) ? v1 : outv;
    float* ncs = (it == 0) ? c1 : outc;

    hipMemsetAsync(aggv, 0, NF * sizeof(float), stream);
    hipMemsetAsync(aggc, 0, NF * sizeof(float), stream);

    edge_pass<<<256, 256, 0, stream>>>(vf, cf, edge_feat, ev, ec,
        w_msg1 + (size_t)it * MSG_IN * H, b_msg1 + (size_t)it * H,
        w_msg2 + (size_t)it * H * F,      b_msg2 + (size_t)it * F,
        aggv, aggc);

    node_update<<<256, 256, 0, stream>>>(vf, aggv,
        w_vupd1 + (size_t)it * H * H, b_vupd1 + (size_t)it * H,
        w_vupd2 + (size_t)it * H * F, b_vupd2 + (size_t)it * F, nv);

    node_update<<<256, 256, 0, stream>>>(cf, aggc,
        w_cupd1 + (size_t)it * H * H, b_cupd1 + (size_t)it * H,
        w_cupd2 + (size_t)it * H * F, b_cupd2 + (size_t)it * F, ncs);
  }
}

// Round 2
// 990.143 us; speedup vs baseline: 4.5676x; 4.5676x over previous
//
#include <hip/hip_runtime.h>

#define N_NODES 50000
#define E_EDGES 800000
#define F 64
#define FE 8
#define H 128
#define MSG_IN 136
#define XPAD 168   // sX row stride in bf16 elems (K padded 136->160, +8 bank spread)
#define HPAD 136   // sHid row stride in bf16 elems

typedef short bf16x8 __attribute__((ext_vector_type(8)));
typedef float f32x4 __attribute__((ext_vector_type(4)));

__device__ __forceinline__ ushort f2bf(float f) {
  uint u = __float_as_uint(f);
  u = (u + 0x7FFFu + ((u >> 16) & 1u)) >> 16;   // RNE
  return (ushort)u;
}
__device__ __forceinline__ uint pack2(float a, float b) {
  return (uint)f2bf(a) | ((uint)f2bf(b) << 16);
}
__device__ __forceinline__ void fma4(float4& a, float x, const float4& w) {
  a.x = fmaf(x, w.x, a.x); a.y = fmaf(x, w.y, a.y);
  a.z = fmaf(x, w.z, a.z); a.w = fmaf(x, w.w, a.w);
}

// ---------------------------------------------------------------------------
// Edge pass (bf16 MFMA): per 64-edge tile, stage X=[vs|cs|ef] bf16 in LDS,
// hidden_v = relu(X@W1+b1); hidden_c via K-block-permuted B-frags (swap of
// the two 64-wide halves of the concat); m = hidden@W2+b2 -> atomic scatter.
// W1/W2 fragments are held in registers, loaded once per block.
// ---------------------------------------------------------------------------
__global__ __launch_bounds__(256, 2)
void edge_pass_mfma(const float* __restrict__ vfeat, const float* __restrict__ cfeat,
                    const float* __restrict__ efeat,
                    const int* __restrict__ ev, const int* __restrict__ ec,
                    const float* __restrict__ w1, const float* __restrict__ b1,
                    const float* __restrict__ w2, const float* __restrict__ b2,
                    float* __restrict__ aggv, float* __restrict__ aggc)
{
  __shared__ __align__(16) ushort sX[64 * XPAD];        // 21504 B
  __shared__ __align__(16) ushort sHid[2 * 64 * HPAD];  // 34816 B
  __shared__ int sIv[64], sIc[64];                      // ~57 KB total -> 2 blocks/CU

  const int t = threadIdx.x;
  const int wid = t >> 6, lane = t & 63;
  const int l15 = lane & 15, hi = lane >> 4;

  // ---- B-fragments in registers (once per block) ----
  // layer1: B[k][n], b[i] = W1[kb*32 + hi*8 + i][col];  layer2 likewise from W2.
  bf16x8 bf1[2][5];
  bf16x8 bf2[4];
  #pragma unroll
  for (int n = 0; n < 2; ++n) {
    const int col = wid * 32 + n * 16 + l15;
    #pragma unroll
    for (int kb = 0; kb < 5; ++kb) {
      #pragma unroll
      for (int i = 0; i < 8; ++i) {
        const int kg = kb * 32 + hi * 8 + i;
        bf1[n][kb][i] = (short)((kg < MSG_IN) ? f2bf(w1[kg * H + col]) : (ushort)0);
      }
    }
  }
  {
    const int col = wid * 16 + l15;
    #pragma unroll
    for (int kb = 0; kb < 4; ++kb) {
      #pragma unroll
      for (int i = 0; i < 8; ++i) {
        const int kg = kb * 32 + hi * 8 + i;
        bf2[kb][i] = (short)f2bf(w2[kg * F + col]);
      }
    }
  }
  const float bb1_0 = b1[wid * 32 + l15];
  const float bb1_1 = b1[wid * 32 + 16 + l15];
  const float bb2   = b2[wid * 16 + l15];

  // zero sX K-pad (cols 136..167) once; only ever written as zero
  {
    uint* xu = (uint*)sX;
    for (int i = t; i < 64 * 16; i += 256) {
      const int row = i >> 4, u = i & 15;
      xu[row * (XPAD / 2) + (MSG_IN / 2) + u] = 0;
    }
  }

  const int nTiles = E_EDGES / 64;   // 12500, exact
  for (int tile = blockIdx.x; tile < nTiles; tile += gridDim.x) {
    __syncthreads();   // sX/sHid reuse guard
    // ---- stage X tile: 4 threads per edge row ----
    {
      const int r = t >> 2, q = t & 3;
      const int e = tile * 64 + r;
      const int iv = ev[e], ic = ec[e];
      if (q == 0) { sIv[r] = iv; sIc[r] = ic; }
      const float4* vp = (const float4*)(vfeat + (size_t)iv * F) + q * 4;
      const float4* cp = (const float4*)(cfeat + (size_t)ic * F) + q * 4;
      uint* xr = (uint*)&sX[r * XPAD];
      #pragma unroll
      for (int j = 0; j < 4; ++j) {
        const float4 v = vp[j];
        xr[q * 8 + j * 2]     = pack2(v.x, v.y);
        xr[q * 8 + j * 2 + 1] = pack2(v.z, v.w);
        const float4 c = cp[j];
        xr[32 + q * 8 + j * 2]     = pack2(c.x, c.y);
        xr[32 + q * 8 + j * 2 + 1] = pack2(c.z, c.w);
      }
      if (q == 0) {
        const float4* ep = (const float4*)(efeat + (size_t)e * FE);
        #pragma unroll
        for (int j = 0; j < 2; ++j) {
          const float4 v = ep[j];
          xr[64 + j * 2]     = pack2(v.x, v.y);
          xr[64 + j * 2 + 1] = pack2(v.z, v.w);
        }
      }
    }
    __syncthreads();

    // ---- layer 1: wave owns hidden cols [wid*32, wid*32+32), all 64 edges ----
    f32x4 accV[4][2], accC[4][2];
    #pragma unroll
    for (int m = 0; m < 4; ++m)
      #pragma unroll
      for (int n = 0; n < 2; ++n) { accV[m][n] = (f32x4)(0.f); accC[m][n] = (f32x4)(0.f); }

    #pragma unroll
    for (int kb = 0; kb < 5; ++kb) {
      constexpr int perm[5] = {2, 3, 0, 1, 4};   // swap 64-wide halves of concat
      #pragma unroll
      for (int m = 0; m < 4; ++m) {
        const bf16x8 a = *(const bf16x8*)&sX[(m * 16 + l15) * XPAD + kb * 32 + hi * 8];
        #pragma unroll
        for (int n = 0; n < 2; ++n) {
          accV[m][n] = __builtin_amdgcn_mfma_f32_16x16x32_bf16(a, bf1[n][kb],       accV[m][n], 0, 0, 0);
          accC[m][n] = __builtin_amdgcn_mfma_f32_16x16x32_bf16(a, bf1[n][perm[kb]], accC[m][n], 0, 0, 0);
        }
      }
    }

    // bias + relu -> sHid (bf16)
    #pragma unroll
    for (int m = 0; m < 4; ++m) {
      #pragma unroll
      for (int n = 0; n < 2; ++n) {
        const int j = wid * 32 + n * 16 + l15;
        const float bj = n ? bb1_1 : bb1_0;
        #pragma unroll
        for (int r = 0; r < 4; ++r) {
          const int edge = m * 16 + hi * 4 + r;
          sHid[edge * HPAD + j]        = f2bf(fmaxf(accV[m][n][r] + bj, 0.f));
          sHid[(64 + edge) * HPAD + j] = f2bf(fmaxf(accC[m][n][r] + bj, 0.f));
        }
      }
    }
    __syncthreads();

    // ---- layer 2: wave owns output cols [wid*16, wid*16+16) ----
    f32x4 acc2[2][4];
    #pragma unroll
    for (int v = 0; v < 2; ++v)
      #pragma unroll
      for (int m = 0; m < 4; ++m) acc2[v][m] = (f32x4)(0.f);

    #pragma unroll
    for (int kb = 0; kb < 4; ++kb) {
      #pragma unroll
      for (int v = 0; v < 2; ++v) {
        #pragma unroll
        for (int m = 0; m < 4; ++m) {
          const bf16x8 a = *(const bf16x8*)&sHid[(v * 64 + m * 16 + l15) * HPAD + kb * 32 + hi * 8];
          acc2[v][m] = __builtin_amdgcn_mfma_f32_16x16x32_bf16(a, bf2[kb], acc2[v][m], 0, 0, 0);
        }
      }
    }

    // ---- scatter: 16 consecutive cols per lane-group -> one 64B line ----
    #pragma unroll
    for (int v = 0; v < 2; ++v) {
      float* agg = v ? aggc : aggv;
      const int* sI = v ? sIc : sIv;
      #pragma unroll
      for (int m = 0; m < 4; ++m) {
        #pragma unroll
        for (int r = 0; r < 4; ++r) {
          const int edge = m * 16 + hi * 4 + r;
          const int idx = sI[edge];
          unsafeAtomicAdd(&agg[(size_t)idx * F + wid * 16 + l15], acc2[v][m][r] + bb2);
        }
      }
    }
  }
}

// ---------------------------------------------------------------------------
// Node update (fp32, unchanged): new_feat = MLP(concat(feat, agg))
// ---------------------------------------------------------------------------
__global__ __launch_bounds__(256, 1)
void node_update(const float* __restrict__ feat, const float* __restrict__ agg,
                 const float* __restrict__ w1, const float* __restrict__ b1,
                 const float* __restrict__ w2, const float* __restrict__ b2,
                 float* __restrict__ out)
{
  __shared__ float sW1[H * H];
  __shared__ float sB1[H];
  __shared__ float sB2[F];
  __shared__ float sX[32 * 132];
  __shared__ float sHt[32 * 132];

  const int t = threadIdx.x;
  for (int i = t; i < H * H; i += 256) sW1[i] = w1[i];
  if (t < H) sB1[t] = b1[t];
  if (t < F) sB2[t] = b2[t];

  const int lane16 = t & 15, grp = t >> 4;
  const int j0 = lane16 * 4;
  const float4* w2v = (const float4*)w2;

  const int nTiles = (N_NODES + 31) / 32;
  for (int tile = blockIdx.x; tile < nTiles; tile += gridDim.x) {
    __syncthreads();
    {
      const int tpr = t & 7, r = t >> 3;
      const int n = tile * 32 + r;
      const int nc = n < N_NODES ? n : N_NODES - 1;
      const float4* fp = (const float4*)(feat + (size_t)nc * F);
      const float4* ap = (const float4*)(agg + (size_t)nc * F);
      float4* xr = (float4*)&sX[r * 132];
      xr[tpr]      = fp[tpr];
      xr[tpr + 8]  = fp[tpr + 8];
      xr[tpr + 16] = ap[tpr];
      xr[tpr + 24] = ap[tpr + 8];
    }
    __syncthreads();

    const int e0 = grp * 2, e1 = e0 + 1;
    float4 a0L = {0,0,0,0}, a0H = {0,0,0,0}, a1L = {0,0,0,0}, a1H = {0,0,0,0};
    const float* x0p = &sX[e0 * 132];
    const float* x1p = &sX[e1 * 132];
    #pragma unroll 4
    for (int k = 0; k < H; ++k) {
      const float x0 = x0p[k], x1 = x1p[k];
      const float4 wL = *(const float4*)&sW1[k * H + j0];
      const float4 wH = *(const float4*)&sW1[k * H + j0 + 64];
      fma4(a0L, x0, wL); fma4(a0H, x0, wH);
      fma4(a1L, x1, wL); fma4(a1H, x1, wH);
    }
    {
      const float4 bL = *(const float4*)&sB1[j0];
      const float4 bH = *(const float4*)&sB1[j0 + 64];
      #define EMITN(row, joff, a, b) { \
        float4 r_ = a; \
        r_.x = fmaxf(r_.x + (b).x, 0.f); r_.y = fmaxf(r_.y + (b).y, 0.f); \
        r_.z = fmaxf(r_.z + (b).z, 0.f); r_.w = fmaxf(r_.w + (b).w, 0.f); \
        *(float4*)&sHt[(row) * 132 + (joff)] = r_; }
      EMITN(e0, j0, a0L, bL); EMITN(e0, j0 + 64, a0H, bH);
      EMITN(e1, j0, a1L, bL); EMITN(e1, j0 + 64, a1H, bH);
      #undef EMITN
    }
    __syncthreads();

    const int f0 = j0;
    float4 a20 = {0,0,0,0}, a21 = {0,0,0,0};
    #pragma unroll 8
    for (int j = 0; j < H; ++j) {
      const float4 w = w2v[j * 16 + lane16];
      fma4(a20, sHt[e0 * 132 + j], w);
      fma4(a21, sHt[e1 * 132 + j], w);
    }
    const float4 b2v = *(const float4*)&sB2[f0];
    const int n0 = tile * 32 + e0;
    if (n0 < N_NODES) {
      float4 o = {a20.x + b2v.x, a20.y + b2v.y, a20.z + b2v.z, a20.w + b2v.w};
      *(float4*)&out[(size_t)n0 * F + f0] = o;
    }
    if (n0 + 1 < N_NODES) {
      float4 o = {a21.x + b2v.x, a21.y + b2v.y, a21.z + b2v.z, a21.w + b2v.w};
      *(float4*)&out[(size_t)(n0 + 1) * F + f0] = o;
    }
  }
}

extern "C" void kernel_launch(void* const* d_in, const int* in_sizes, int n_in,
                              void* d_out, int out_size, void* d_ws, size_t ws_size,
                              hipStream_t stream) {
  const float* var_feat  = (const float*)d_in[0];
  const float* cons_feat = (const float*)d_in[1];
  const float* edge_feat = (const float*)d_in[2];
  const int*   ev        = (const int*)d_in[3];
  const int*   ec        = (const int*)d_in[4];
  const float* w_msg1  = (const float*)d_in[5];
  const float* b_msg1  = (const float*)d_in[6];
  const float* w_msg2  = (const float*)d_in[7];
  const float* b_msg2  = (const float*)d_in[8];
  const float* w_vupd1 = (const float*)d_in[9];
  const float* b_vupd1 = (const float*)d_in[10];
  const float* w_vupd2 = (const float*)d_in[11];
  const float* b_vupd2 = (const float*)d_in[12];
  const float* w_cupd1 = (const float*)d_in[13];
  const float* b_cupd1 = (const float*)d_in[14];
  const float* w_cupd2 = (const float*)d_in[15];
  const float* b_cupd2 = (const float*)d_in[16];

  const size_t NF = (size_t)N_NODES * F;
  float* aggv = (float*)d_ws;
  float* aggc = aggv + NF;
  float* v1   = aggc + NF;
  float* c1   = v1 + NF;
  float* outv = (float*)d_out;
  float* outc = outv + NF;

  for (int it = 0; it < 2; ++it) {
    const float* vf = (it == 0) ? var_feat : v1;
    const float* cf = (it == 0) ? cons_feat : c1;
    float* nv  = (it == 0) ? v1 : outv;
    float* ncs = (it == 0) ? c1 : outc;

    hipMemsetAsync(aggv, 0, NF * sizeof(float), stream);
    hipMemsetAsync(aggc, 0, NF * sizeof(float), stream);

    edge_pass_mfma<<<512, 256, 0, stream>>>(vf, cf, edge_feat, ev, ec,
        w_msg1 + (size_t)it * MSG_IN * H, b_msg1 + (size_t)it * H,
        w_msg2 + (size_t)it * H * F,      b_msg2 + (size_t)it * F,
        aggv, aggc);

    node_update<<<256, 256, 0, stream>>>(vf, aggv,
        w_vupd1 + (size_t)it * H * H, b_vupd1 + (size_t)it * H,
        w_vupd2 + (size_t)it * H * F, b_vupd2 + (size_t)it * F, nv);

    node_update<<<256, 256, 0, stream>>>(cf, aggc,
        w_cupd1 + (size_t)it * H * H, b_cupd1 + (size_t)it * H,
        w_cupd2 + (size_t)it * H * F, b_cupd2 + (size_t)it * F, ncs);
  }
}

// Round 3
// 775.787 us; speedup vs baseline: 5.8297x; 1.2763x over previous
//
#include <hip/hip_runtime.h>

#define N_NODES 50000
#define E_EDGES 800000
#define F 64
#define FE 8
#define H 128
#define MSG_IN 136
#define XPAD 168   // ushorts per sX row (K zero-padded 136->160, +8 spread); 336B, 16B-aligned
#define HPW 68     // dwords per packed-hidden row (64 data + 4 pad); 272B, 16B-aligned
#define NXP 136    // ushorts per node sX row (128 data + 8 spread); 272B, 16B-aligned

typedef short bf16x8 __attribute__((ext_vector_type(8)));
typedef float f32x4 __attribute__((ext_vector_type(4)));

__device__ __forceinline__ ushort f2bf(float f) {
  uint u = __float_as_uint(f);
  u = (u + 0x7FFFu + ((u >> 16) & 1u)) >> 16;   // RNE
  return (ushort)u;
}
__device__ __forceinline__ uint pack2(float a, float b) {
  return (uint)f2bf(a) | ((uint)f2bf(b) << 16);
}

// ---------------------------------------------------------------------------
// Edge pass (bf16 MFMA, reg-prefetch pipelined).
// Layer1: hid = relu(X@W1+b1) twice (v-side, c-side via K-block-permuted B
// frags). Hidden stored packed: u32 at [edge][wid*16+l15] = (j, j+16) bf16
// pair; layer2 W2 B-frags are loaded with the matching k-slot permutation.
// Layer2: wave owns (side, f-half); scatter via fp32 HW atomics.
// ---------------------------------------------------------------------------
__global__ __launch_bounds__(256, 2)
void edge_pass_mfma(const float* __restrict__ vfeat, const float* __restrict__ cfeat,
                    const float* __restrict__ efeat,
                    const int* __restrict__ ev, const int* __restrict__ ec,
                    const float* __restrict__ w1, const float* __restrict__ b1,
                    const float* __restrict__ w2, const float* __restrict__ b2,
                    float* __restrict__ aggv, float* __restrict__ aggc)
{
  __shared__ __align__(16) ushort sX[64 * XPAD];   // 21504 B
  __shared__ __align__(16) uint  sH[128 * HPW];    // 34816 B
  __shared__ int sIv[64], sIc[64];                 // ~56.8 KB -> 2 blocks/CU

  const int t = threadIdx.x;
  const int wid = t >> 6, l15 = t & 15, hi = (t >> 4) & 3;

  // ---- layer-1 W1 B-frags: col = wid*32 + n*16 + l15, slot k = kb*32+hi*8+i
  bf16x8 bf1[2][5];
  #pragma unroll
  for (int n = 0; n < 2; ++n) {
    const int col = wid * 32 + n * 16 + l15;
    #pragma unroll
    for (int kb = 0; kb < 5; ++kb)
      #pragma unroll
      for (int i = 0; i < 8; ++i) {
        const int kg = kb * 32 + hi * 8 + i;
        bf1[n][kb][i] = (short)((kg < MSG_IN) ? f2bf(w1[kg * H + col]) : (ushort)0);
      }
  }
  // ---- layer-2 W2 B-frags (f-half per wave) with packed-k slot permutation:
  // ushort slot p = hi*8+i  <->  k_local = (p>>1) | ((p&1)<<4)
  const int fh = wid & 1;           // f-half: cols [fh*32, fh*32+32)
  const int vSide = wid >> 1;       // 0 = var-msg rows, 1 = cons-msg rows
  bf16x8 bf2[2][4];                 // [f-block in half][kb]
  #pragma unroll
  for (int fbl = 0; fbl < 2; ++fbl) {
    const int col = fh * 32 + fbl * 16 + l15;
    #pragma unroll
    for (int kb = 0; kb < 4; ++kb)
      #pragma unroll
      for (int i = 0; i < 8; ++i) {
        const int p = hi * 8 + i;
        const int kl = (p >> 1) | ((p & 1) << 4);
        bf2[fbl][kb][i] = (short)f2bf(w2[(kb * 32 + kl) * F + col]);
      }
  }
  const float bb1[2] = { b1[wid * 32 + l15], b1[wid * 32 + 16 + l15] };
  const float bb2[2] = { b2[fh * 32 + l15], b2[fh * 32 + 16 + l15] };

  // zero the K-pad dwords [68,84) of every sX row (once; never overwritten)
  {
    uint* xu = (uint*)sX;
    for (int i = t; i < 64 * 16; i += 256) {
      const int row = i >> 4, u = i & 15;
      xu[row * (XPAD / 2) + 68 + u] = 0;
    }
  }

  // ---- staging role + prefetch prologue ----
  const int r = t >> 2, q = t & 3;
  const int g = gridDim.x;
  const int nTiles = E_EDGES / 64;   // 12500 exact

  int tile = blockIdx.x;             // always < nTiles (grid 512)
  int ivC = ev[tile * 64 + r], icC = ec[tile * 64 + r];
  const int tn0 = min(tile + g, nTiles - 1);
  int ivN = ev[tn0 * 64 + r], icN = ec[tn0 * 64 + r];
  float4 fv[4], fc[4], fe0, fe1;
  {
    const float4* vp = (const float4*)(vfeat + (size_t)ivC * F) + q * 4;
    const float4* cp = (const float4*)(cfeat + (size_t)icC * F) + q * 4;
    #pragma unroll
    for (int j = 0; j < 4; ++j) { fv[j] = vp[j]; fc[j] = cp[j]; }
    if (q == 0) {
      const float4* ep = (const float4*)(efeat + (size_t)(tile * 64 + r) * FE);
      fe0 = ep[0]; fe1 = ep[1];
    }
  }

  for (; tile < nTiles; tile += g) {
    __syncthreads();   // sX / sH free
    // ---- write staged tile -> sX ----
    if (q == 0) { sIv[r] = ivC; sIc[r] = icC; }
    {
      uint* xr = (uint*)&sX[r * XPAD];
      #pragma unroll
      for (int j = 0; j < 4; ++j) {
        xr[q * 8 + j * 2]          = pack2(fv[j].x, fv[j].y);
        xr[q * 8 + j * 2 + 1]      = pack2(fv[j].z, fv[j].w);
        xr[32 + q * 8 + j * 2]     = pack2(fc[j].x, fc[j].y);
        xr[32 + q * 8 + j * 2 + 1] = pack2(fc[j].z, fc[j].w);
      }
      if (q == 0) {
        xr[64] = pack2(fe0.x, fe0.y); xr[65] = pack2(fe0.z, fe0.w);
        xr[66] = pack2(fe1.x, fe1.y); xr[67] = pack2(fe1.z, fe1.w);
      }
    }
    // ---- rotate + issue prefetch for tile+g (idx for tile+2g) ----
    ivC = ivN; icC = icN;
    {
      const int t2 = min(tile + 2 * g, nTiles - 1);
      ivN = ev[t2 * 64 + r]; icN = ec[t2 * 64 + r];
      const float4* vp = (const float4*)(vfeat + (size_t)ivC * F) + q * 4;
      const float4* cp = (const float4*)(cfeat + (size_t)icC * F) + q * 4;
      #pragma unroll
      for (int j = 0; j < 4; ++j) { fv[j] = vp[j]; fc[j] = cp[j]; }
      if (q == 0) {
        const int en = min(tile + g, nTiles - 1) * 64 + r;
        const float4* ep = (const float4*)(efeat + (size_t)en * FE);
        fe0 = ep[0]; fe1 = ep[1];
      }
    }
    __syncthreads();   // sX ready

    // ---- layer 1: wave owns hidden cols [wid*32, wid*32+32), all 64 edges ----
    f32x4 aV[4][2], aC[4][2];
    #pragma unroll
    for (int m = 0; m < 4; ++m)
      #pragma unroll
      for (int n = 0; n < 2; ++n) { aV[m][n] = (f32x4)(0.f); aC[m][n] = (f32x4)(0.f); }

    constexpr int perm[5] = {2, 3, 0, 1, 4};   // swap 64-wide halves of the concat
    #pragma unroll
    for (int kb = 0; kb < 5; ++kb) {
      #pragma unroll
      for (int m = 0; m < 4; ++m) {
        const bf16x8 a = *(const bf16x8*)&sX[(m * 16 + l15) * XPAD + kb * 32 + hi * 8];
        #pragma unroll
        for (int n = 0; n < 2; ++n) {
          aV[m][n] = __builtin_amdgcn_mfma_f32_16x16x32_bf16(a, bf1[n][kb],       aV[m][n], 0, 0, 0);
          aC[m][n] = __builtin_amdgcn_mfma_f32_16x16x32_bf16(a, bf1[n][perm[kb]], aC[m][n], 0, 0, 0);
        }
      }
    }
    // bias+relu, packed u32 write: dword [edge][wid*16 + l15] = (j, j+16)
    #pragma unroll
    for (int m = 0; m < 4; ++m)
      #pragma unroll
      for (int rr = 0; rr < 4; ++rr) {
        const int e = m * 16 + hi * 4 + rr;
        sH[e * HPW + wid * 16 + l15] =
            pack2(fmaxf(aV[m][0][rr] + bb1[0], 0.f), fmaxf(aV[m][1][rr] + bb1[1], 0.f));
        sH[(64 + e) * HPW + wid * 16 + l15] =
            pack2(fmaxf(aC[m][0][rr] + bb1[0], 0.f), fmaxf(aC[m][1][rr] + bb1[1], 0.f));
      }
    __syncthreads();   // sH ready

    // ---- layer 2: wave owns (side, f-half); 16 A-reads, 32 MFMA ----
    f32x4 a2[4][2];
    #pragma unroll
    for (int m = 0; m < 4; ++m)
      #pragma unroll
      for (int fbl = 0; fbl < 2; ++fbl) a2[m][fbl] = (f32x4)(0.f);

    const ushort* sHu = (const ushort*)sH;
    #pragma unroll
    for (int kb = 0; kb < 4; ++kb)
      #pragma unroll
      for (int m = 0; m < 4; ++m) {
        const int e = vSide * 64 + m * 16 + l15;
        const bf16x8 a = *(const bf16x8*)&sHu[e * (HPW * 2) + kb * 32 + hi * 8];
        #pragma unroll
        for (int fbl = 0; fbl < 2; ++fbl)
          a2[m][fbl] = __builtin_amdgcn_mfma_f32_16x16x32_bf16(a, bf2[fbl][kb], a2[m][fbl], 0, 0, 0);
      }

    float* agg = vSide ? aggc : aggv;
    const int* sI = vSide ? sIc : sIv;
    #pragma unroll
    for (int m = 0; m < 4; ++m)
      #pragma unroll
      for (int rr = 0; rr < 4; ++rr) {
        const int idx = sI[m * 16 + hi * 4 + rr];
        float* dst = agg + (size_t)idx * F + fh * 32 + l15;
        unsafeAtomicAdd(dst,      a2[m][0][rr] + bb2[0]);
        unsafeAtomicAdd(dst + 16, a2[m][1][rr] + bb2[1]);
      }
  }
}

// ---------------------------------------------------------------------------
// Node update (bf16 MFMA): new_feat = MLP(concat(feat, agg)), 64-node tiles.
// ---------------------------------------------------------------------------
__global__ __launch_bounds__(256, 2)
void node_update_mfma(const float* __restrict__ feat, const float* __restrict__ agg,
                      const float* __restrict__ w1, const float* __restrict__ b1,
                      const float* __restrict__ w2, const float* __restrict__ b2,
                      float* __restrict__ out)
{
  __shared__ __align__(16) ushort sX[64 * NXP];   // 17408 B
  __shared__ __align__(16) uint  sH[64 * HPW];    // 17408 B

  const int t = threadIdx.x;
  const int wid = t >> 6, l15 = t & 15, hi = (t >> 4) & 3;

  bf16x8 bf1[2][4];
  #pragma unroll
  for (int n = 0; n < 2; ++n) {
    const int col = wid * 32 + n * 16 + l15;
    #pragma unroll
    for (int kb = 0; kb < 4; ++kb)
      #pragma unroll
      for (int i = 0; i < 8; ++i)
        bf1[n][kb][i] = (short)f2bf(w1[(kb * 32 + hi * 8 + i) * H + col]);
  }
  bf16x8 bf2[4][4];   // wave owns row-block wid, all 4 f-blocks
  #pragma unroll
  for (int fb = 0; fb < 4; ++fb) {
    const int col = fb * 16 + l15;
    #pragma unroll
    for (int kb = 0; kb < 4; ++kb)
      #pragma unroll
      for (int i = 0; i < 8; ++i) {
        const int p = hi * 8 + i;
        const int kl = (p >> 1) | ((p & 1) << 4);
        bf2[fb][kb][i] = (short)f2bf(w2[(kb * 32 + kl) * F + col]);
      }
  }
  const float bb1[2] = { b1[wid * 32 + l15], b1[wid * 32 + 16 + l15] };
  const float bb2[4] = { b2[l15], b2[16 + l15], b2[32 + l15], b2[48 + l15] };

  const int r = t >> 2, q = t & 3;
  const int nTiles = (N_NODES + 63) / 64;   // 782
  for (int tile = blockIdx.x; tile < nTiles; tile += gridDim.x) {
    __syncthreads();
    {
      const int node = tile * 64 + r;
      const int nc = node < N_NODES ? node : N_NODES - 1;
      const float4* fp = (const float4*)(feat + (size_t)nc * F) + q * 4;
      const float4* ap = (const float4*)(agg  + (size_t)nc * F) + q * 4;
      uint* xr = (uint*)&sX[r * NXP];
      #pragma unroll
      for (int j = 0; j < 4; ++j) {
        const float4 a = fp[j], b = ap[j];
        xr[q * 8 + j * 2]          = pack2(a.x, a.y);
        xr[q * 8 + j * 2 + 1]      = pack2(a.z, a.w);
        xr[32 + q * 8 + j * 2]     = pack2(b.x, b.y);
        xr[32 + q * 8 + j * 2 + 1] = pack2(b.z, b.w);
      }
    }
    __syncthreads();

    f32x4 aV[4][2];
    #pragma unroll
    for (int m = 0; m < 4; ++m)
      #pragma unroll
      for (int n = 0; n < 2; ++n) aV[m][n] = (f32x4)(0.f);
    #pragma unroll
    for (int kb = 0; kb < 4; ++kb)
      #pragma unroll
      for (int m = 0; m < 4; ++m) {
        const bf16x8 a = *(const bf16x8*)&sX[(m * 16 + l15) * NXP + kb * 32 + hi * 8];
        #pragma unroll
        for (int n = 0; n < 2; ++n)
          aV[m][n] = __builtin_amdgcn_mfma_f32_16x16x32_bf16(a, bf1[n][kb], aV[m][n], 0, 0, 0);
      }
    #pragma unroll
    for (int m = 0; m < 4; ++m)
      #pragma unroll
      for (int rr = 0; rr < 4; ++rr) {
        const int e = m * 16 + hi * 4 + rr;
        sH[e * HPW + wid * 16 + l15] =
            pack2(fmaxf(aV[m][0][rr] + bb1[0], 0.f), fmaxf(aV[m][1][rr] + bb1[1], 0.f));
      }
    __syncthreads();

    f32x4 a2[4];
    #pragma unroll
    for (int fb = 0; fb < 4; ++fb) a2[fb] = (f32x4)(0.f);
    const ushort* sHu = (const ushort*)sH;
    #pragma unroll
    for (int kb = 0; kb < 4; ++kb) {
      const int e = wid * 16 + l15;
      const bf16x8 a = *(const bf16x8*)&sHu[e * (HPW * 2) + kb * 32 + hi * 8];
      #pragma unroll
      for (int fb = 0; fb < 4; ++fb)
        a2[fb] = __builtin_amdgcn_mfma_f32_16x16x32_bf16(a, bf2[fb][kb], a2[fb], 0, 0, 0);
    }
    #pragma unroll
    for (int rr = 0; rr < 4; ++rr) {
      const int node = tile * 64 + wid * 16 + hi * 4 + rr;
      if (node < N_NODES) {
        #pragma unroll
        for (int fb = 0; fb < 4; ++fb)
          out[(size_t)node * F + fb * 16 + l15] = a2[fb][rr] + bb2[fb];
      }
    }
  }
}

extern "C" void kernel_launch(void* const* d_in, const int* in_sizes, int n_in,
                              void* d_out, int out_size, void* d_ws, size_t ws_size,
                              hipStream_t stream) {
  const float* var_feat  = (const float*)d_in[0];
  const float* cons_feat = (const float*)d_in[1];
  const float* edge_feat = (const float*)d_in[2];
  const int*   ev        = (const int*)d_in[3];
  const int*   ec        = (const int*)d_in[4];
  const float* w_msg1  = (const float*)d_in[5];
  const float* b_msg1  = (const float*)d_in[6];
  const float* w_msg2  = (const float*)d_in[7];
  const float* b_msg2  = (const float*)d_in[8];
  const float* w_vupd1 = (const float*)d_in[9];
  const float* b_vupd1 = (const float*)d_in[10];
  const float* w_vupd2 = (const float*)d_in[11];
  const float* b_vupd2 = (const float*)d_in[12];
  const float* w_cupd1 = (const float*)d_in[13];
  const float* b_cupd1 = (const float*)d_in[14];
  const float* w_cupd2 = (const float*)d_in[15];
  const float* b_cupd2 = (const float*)d_in[16];

  const size_t NF = (size_t)N_NODES * F;
  float* aggv = (float*)d_ws;
  float* aggc = aggv + NF;
  float* v1   = aggc + NF;
  float* c1   = v1 + NF;
  float* outv = (float*)d_out;
  float* outc = outv + NF;

  for (int it = 0; it < 2; ++it) {
    const float* vf = (it == 0) ? var_feat : v1;
    const float* cf = (it == 0) ? cons_feat : c1;
    float* nv  = (it == 0) ? v1 : outv;
    float* ncs = (it == 0) ? c1 : outc;

    hipMemsetAsync(aggv, 0, NF * sizeof(float), stream);
    hipMemsetAsync(aggc, 0, NF * sizeof(float), stream);

    edge_pass_mfma<<<512, 256, 0, stream>>>(vf, cf, edge_feat, ev, ec,
        w_msg1 + (size_t)it * MSG_IN * H, b_msg1 + (size_t)it * H,
        w_msg2 + (size_t)it * H * F,      b_msg2 + (size_t)it * F,
        aggv, aggc);

    node_update_mfma<<<782, 256, 0, stream>>>(vf, aggv,
        w_vupd1 + (size_t)it * H * H, b_vupd1 + (size_t)it * H,
        w_vupd2 + (size_t)it * H * F, b_vupd2 + (size_t)it * F, nv);

    node_update_mfma<<<782, 256, 0, stream>>>(cf, aggc,
        w_cupd1 + (size_t)it * H * H, b_cupd1 + (size_t)it * H,
        w_cupd2 + (size_t)it * H * F, b_cupd2 + (size_t)it * F, ncs);
  }
}